// Round 3
// baseline (403.014 us; speedup 1.0000x reference)
//
#include <hip/hip_runtime.h>

// Problem constants (fixed by reference setup_inputs)
constexpr int B  = 4;
constexpr int C  = 128;    // == Cv
constexpr int hw = 16384;  // h*w = 128*128
constexpr int W_ = 256;
constexpr int HW = 65536;  // H*W
constexpr int K  = 16;
constexpr int P_TILE = 16;                       // positions per block
constexpr int BLOCKS_PER_BATCH = hw / P_TILE;    // 1024

typedef __attribute__((ext_vector_type(8))) _Float16 half8;

// Transpose+convert: S,R fp32 (C,HW) -> interleaved fp16 KV (HW, 256) per batch.
// KV[n][c] = S[c][n] for c<128, = R[c-128][n] for c>=128.
// One 64x64 (c,n) tile per (blockIdx.x, blockIdx.y), both tensors sequentially
// through a SINGLE 16.6KB LDS tile (8 blocks/CU -> full occupancy).
//   stage: float4 global reads (16B/lane), scalar ds_writes (2-way banks = free)
//   drain: 8 scalar LDS column reads/lane (2-way banks = free) -> half8 pack
//          -> 16B/lane global store (8 full 128B segments per wave)
__global__ __launch_bounds__(256) void transpose_kv_f16(
    const float* __restrict__ S, const float* __restrict__ R,
    _Float16* __restrict__ KV)
{
    __shared__ float tile[64][65];
    const int z   = blockIdx.z;          // batch
    const int n0  = blockIdx.x * 64;
    const int c0  = blockIdx.y * 64;     // 0 or 64
    const int tid = threadIdx.x;         // 0..255
    _Float16* dbase = KV + (size_t)z * HW * 256;

    const float* srcs[2] = { S + (size_t)z * C * HW, R + (size_t)z * C * HW };

    #pragma unroll
    for (int t = 0; t < 2; ++t) {
        const float* s = srcs[t];
        // ---- stage: 64 rows x 64 cols, float4 per lane ----
        #pragma unroll
        for (int i = 0; i < 4; ++i) {
            const int cl = (tid >> 4) + i * 16;      // 0..63 channel row
            const int x0 = (tid & 15) * 4;           // col within tile
            const float4 v = *reinterpret_cast<const float4*>(
                &s[(size_t)(c0 + cl) * HW + n0 + x0]);   // coalesced 16B/lane
            tile[cl][x0]     = v.x;                  // scalar ds_writes: bank
            tile[cl][x0 + 1] = v.y;                  // (cl+4tx+j)%32, 64 lanes ->
            tile[cl][x0 + 2] = v.z;                  // 2 lanes/bank = free
            tile[cl][x0 + 3] = v.w;
        }
        __syncthreads();
        // ---- drain: half8 per lane = 8 channels of one n-row ----
        #pragma unroll
        for (int it = 0; it < 2; ++it) {
            const int nl = (tid >> 3) + it * 32;     // 0..63 n-row
            const int u  = tid & 7;                  // 8-channel group
            half8 hv;
            #pragma unroll
            for (int i = 0; i < 8; ++i)              // banks (8u+i+nl)%32: 2-way free
                hv[i] = (_Float16)tile[8 * u + i][nl];
            *reinterpret_cast<half8*>(
                dbase + (size_t)(n0 + nl) * 256 + t * 128 + c0 + 8 * u) = hv;
        }
        __syncthreads();   // protect re-stage of tile for t=1
    }
}

// Fused single-pass gather attention from interleaved fp16 KV rows.
// Per 16-lane group (one position p): for each of 16 gather rows, the group
// loads the full 512B K|V record cooperatively (2x16B per lane), computes the
// score via butterfly reduce, and online-softmax-accumulates V (flash-style
// running m, l). 8 rows (16 loads/lane) in flight to hide gather latency.
__global__ __launch_bounds__(256) void attn_gather_kv(
    const float* __restrict__ Q, const int* __restrict__ Pos,
    const _Float16* __restrict__ KV,
    float* __restrict__ outBuf, float* __restrict__ outM, int b0)
{
    __shared__ float q_s[P_TILE][132];   // Q tile, fp32, padded
    __shared__ float out_s[P_TILE][132];

    const int tid = threadIdx.x;
    const int bb  = blockIdx.x / BLOCKS_PER_BATCH;   // batch within this launch
    const int b   = b0 + bb;                         // absolute batch
    const int p0  = (blockIdx.x % BLOCKS_PER_BATCH) * P_TILE;

    // ---- stage Q tile (coalesced) ----
    for (int i = tid; i < P_TILE * C; i += 256) {
        int c = i >> 4, pl0 = i & 15;
        q_s[pl0][c] = Q[((size_t)(b * C + c)) * hw + p0 + pl0];
    }
    const int pl = tid >> 4;   // position in tile (= 16-lane group id)
    const int cg = tid & 15;   // lane within group
    const int p  = p0 + pl;
    int myidx;
    {
        const int rr = Pos[(((size_t)(b * 2 + 0) * hw) + p) * K + cg];   // coalesced
        const int cc = Pos[(((size_t)(b * 2 + 1) * hw) + p) * K + cg];
        myidx = rr * W_ + cc;
    }
    __syncthreads();

    float qf[8];
    #pragma unroll
    for (int i = 0; i < 8; ++i) qf[i] = q_s[pl][cg * 8 + i];

    float m = -1e30f, l = 0.f, myscore = 0.f;
    float acc[8];
    #pragma unroll
    for (int i = 0; i < 8; ++i) acc[i] = 0.f;

    const half8* base = reinterpret_cast<const half8*>(KV) + (size_t)bb * HW * 32;

    #pragma unroll
    for (int kc = 0; kc < K; kc += 8) {          // 8-row chunks: 16 loads in flight
        half8 kreg[8], vreg[8];
        #pragma unroll
        for (int r = 0; r < 8; ++r) {
            const int ridx = __shfl(myidx, kc + r, 16);    // group-uniform row idx
            const half8* row = base + (size_t)ridx * 32;   // 512B record, 512B aligned
            kreg[r] = row[cg];        // K halfs [cg*8, cg*8+8)
            vreg[r] = row[16 + cg];   // V halfs [cg*8, cg*8+8)
        }
        #pragma unroll
        for (int r = 0; r < 8; ++r) {
            float part = 0.f;
            #pragma unroll
            for (int i = 0; i < 8; ++i) part += qf[i] * (float)kreg[r][i];
            #pragma unroll
            for (int off = 1; off < 16; off <<= 1) part += __shfl_xor(part, off);
            // 'part' = score of row kc+r, identical across the 16-lane group
            const float mn    = fmaxf(m, part);
            const float scale = __expf(m - mn);      // ==1 when max unchanged; 0 on first row
            const float e     = __expf(part - mn);
            l = l * scale + e;
            #pragma unroll
            for (int i = 0; i < 8; ++i) acc[i] = acc[i] * scale + e * (float)vreg[r][i];
            m = mn;
            if (cg == kc + r) myscore = part;
        }
    }

    const float inv_l = 1.0f / l;
    const float attn  = __expf(myscore - m) * inv_l;   // == e_k / sum_k e_k
    outM[((size_t)b * hw + p) * K + cg] = attn;        // coalesced
    #pragma unroll
    for (int i = 0; i < 8; ++i) out_s[pl][cg * 8 + i] = acc[i] * inv_l;
    __syncthreads();
    for (int i = tid; i < P_TILE * C; i += 256) {
        int c = i >> 4, pl3 = i & 15;
        outBuf[((size_t)(b * C + c)) * hw + p0 + pl3] = out_s[pl3][c];   // coalesced
    }
}

// Fallback: direct gather from original (B,C,H,W) layout. Slow but needs no workspace.
__global__ __launch_bounds__(256) void attn_direct(
    const float* __restrict__ Q, const float* __restrict__ S, const float* __restrict__ R,
    const int* __restrict__ Pos, float* __restrict__ outBuf, float* __restrict__ outM)
{
    __shared__ float q_s[P_TILE][132];
    __shared__ float attn_s[P_TILE][17];
    __shared__ int   idx_s[P_TILE][K];
    __shared__ float out_s[P_TILE][132];

    const int tid = threadIdx.x;
    const int b   = blockIdx.x / BLOCKS_PER_BATCH;
    const int p0  = (blockIdx.x % BLOCKS_PER_BATCH) * P_TILE;

    for (int i = tid; i < P_TILE * C; i += 256) {
        int c = i >> 4, pl0 = i & 15;
        q_s[pl0][c] = Q[((size_t)(b * C + c)) * hw + p0 + pl0];
    }
    const int pl = tid >> 4;
    const int kk = tid & 15;
    const int p  = p0 + pl;
    const int rr = Pos[(((size_t)(b * 2 + 0) * hw) + p) * K + kk];
    const int cc = Pos[(((size_t)(b * 2 + 1) * hw) + p) * K + kk];
    const int idx = rr * W_ + cc;
    idx_s[pl][kk] = idx;
    __syncthreads();

    float score = 0.f;
    {
        const float* srow = S + (size_t)b * C * HW + idx;
        for (int c = 0; c < C; ++c) score += q_s[pl][c] * srow[(size_t)c * HW];
    }
    float mx = score;
    #pragma unroll
    for (int off = 1; off < 16; off <<= 1) mx = fmaxf(mx, __shfl_xor(mx, off));
    float e = __expf(score - mx);
    float ssum = e;
    #pragma unroll
    for (int off = 1; off < 16; off <<= 1) ssum += __shfl_xor(ssum, off);
    const float attn = e / ssum;
    outM[((size_t)b * hw + p) * K + kk] = attn;
    attn_s[pl][kk] = attn;
    __syncthreads();

    {
        const int pl2 = tid >> 4;
        const int cg  = tid & 15;
        float acc[8];
        #pragma unroll
        for (int i = 0; i < 8; ++i) acc[i] = 0.f;
        for (int k2 = 0; k2 < K; ++k2) {
            const float a = attn_s[pl2][k2];
            const float* rw = R + (size_t)b * C * HW + idx_s[pl2][k2];
            #pragma unroll
            for (int i = 0; i < 8; ++i) acc[i] += a * rw[(size_t)(cg * 8 + i) * HW];
        }
        #pragma unroll
        for (int i = 0; i < 8; ++i) out_s[pl2][cg * 8 + i] = acc[i];
    }
    __syncthreads();
    for (int i = tid; i < P_TILE * C; i += 256) {
        int c = i >> 4, pl3 = i & 15;
        outBuf[((size_t)(b * C + c)) * hw + p0 + pl3] = out_s[pl3][c];
    }
}

extern "C" void kernel_launch(void* const* d_in, const int* in_sizes, int n_in,
                              void* d_out, int out_size, void* d_ws, size_t ws_size,
                              hipStream_t stream)
{
    (void)in_sizes; (void)n_in; (void)out_size;
    const float* Q  = (const float*)d_in[0];
    const float* S  = (const float*)d_in[1];
    const float* R  = (const float*)d_in[2];
    const int*  Pos = (const int*)d_in[3];
    float* outBuf = (float*)d_out;
    float* outM   = outBuf + (size_t)B * C * hw;   // buffer is B*Cv*h*w elements

    const size_t fullBytes     = (size_t)B * HW * 256 * sizeof(_Float16);  // 128 MiB
    const size_t perBatchBytes = (size_t)HW * 256 * sizeof(_Float16);      // 32 MiB

    dim3 tb(256);
    if (ws_size >= fullBytes) {
        // convert+interleave all batches in one launch, then one fused compute launch
        _Float16* KVt = (_Float16*)d_ws;
        dim3 tg(HW / 64, C / 64, B);
        transpose_kv_f16<<<tg, tb, 0, stream>>>(S, R, KVt);
        attn_gather_kv<<<dim3(B * BLOCKS_PER_BATCH), 256, 0, stream>>>(
            Q, Pos, KVt, outBuf, outM, 0);
    } else if (ws_size >= perBatchBytes) {
        // per-batch convert + compute, workspace reused
        _Float16* KVt = (_Float16*)d_ws;
        dim3 tg(HW / 64, C / 64, 1);
        for (int b = 0; b < B; ++b) {
            transpose_kv_f16<<<tg, tb, 0, stream>>>(
                S + (size_t)b * C * HW, R + (size_t)b * C * HW, KVt);
            attn_gather_kv<<<dim3(BLOCKS_PER_BATCH), 256, 0, stream>>>(
                Q, Pos, KVt, outBuf, outM, b);
        }
    } else {
        // no usable workspace: direct (uncoalesced) fp32 gather
        attn_direct<<<dim3(B * BLOCKS_PER_BATCH), 256, 0, stream>>>(
            Q, S, R, Pos, outBuf, outM);
    }
}

// Round 4
// 397.381 us; speedup vs baseline: 1.0142x; 1.0142x over previous
//
#include <hip/hip_runtime.h>

// Problem constants (fixed by reference setup_inputs)
constexpr int B  = 4;
constexpr int C  = 128;    // == Cv
constexpr int hw = 16384;  // h*w = 128*128
constexpr int W_ = 256;
constexpr int HW = 65536;  // H*W
constexpr int K  = 16;
constexpr int P_TILE = 16;                       // positions per block
constexpr int BLOCKS_PER_BATCH = hw / P_TILE;    // 1024

typedef __attribute__((ext_vector_type(4))) _Float16 half4v;
typedef __attribute__((ext_vector_type(8))) _Float16 half8;

// Transpose+convert: S,R fp32 (C,HW) -> interleaved fp16 KV (HW, 256) per batch.
// KV[n][c] = S[c][n] for c<128, = R[c-128][n] for c>=128.
//
// DRAM-page-friendly decomposition: ONE block builds COMPLETE 512B records for
// 128 consecutive n -> the 64KiB output region is written as one fully-dense
// contiguous burst (one page activation per 2KiB page). Reads get a 512B span
// per channel-row (2x the old 256B).
//
// LDS: kv[ch][n] fp16, 256x128 = 64KiB, n-group XOR-swizzled by (ch>>3):
//   stage:  half4 ds_write_b64 at n' = n4 ^ (ch>>3)  -> floor-rate, no conflict
//   drain:  8x ds_read_u16 per lane; the two records of a wave share the same
//           word (broadcast), banks spread by q^u -> ~2-way (free).
// S-stage and R-stage touch disjoint LDS -> single barrier in the kernel.
__global__ __launch_bounds__(256) void transpose_kv_f16(
    const float* __restrict__ S, const float* __restrict__ R,
    _Float16* __restrict__ KV)
{
    __shared__ _Float16 kv[256 * 128];   // [ch][n-swizzled], 64 KiB
    const int z   = blockIdx.z;          // batch
    const int n0  = blockIdx.x * 128;
    const int tid = threadIdx.x;         // 0..255
    const int n4  = tid & 31;            // n-group of 4 floats (16B)
    const int rg  = tid >> 5;            // 0..7 channel sub-row

    const float* s = S + (size_t)z * C * HW;
    const float* r = R + (size_t)z * C * HW;

    // ---- stage: S -> ch 0..127, R -> ch 128..255 (fp32 -> fp16) ----
    #pragma unroll
    for (int i = 0; i < 16; ++i) {
        const int cl = rg + 8 * i;       // 0..127
        const float4 vs = *reinterpret_cast<const float4*>(
            &s[(size_t)cl * HW + n0 + 4 * n4]);              // 512B span per row
        const float4 vr = *reinterpret_cast<const float4*>(
            &r[(size_t)cl * HW + n0 + 4 * n4]);
        const int chS = cl;
        const int chR = cl + 128;
        const int npS = n4 ^ ((chS >> 3) & 31);
        const int npR = n4 ^ ((chR >> 3) & 31);
        half4v hs, hr;
        hs[0] = (_Float16)vs.x; hs[1] = (_Float16)vs.y;
        hs[2] = (_Float16)vs.z; hs[3] = (_Float16)vs.w;
        hr[0] = (_Float16)vr.x; hr[1] = (_Float16)vr.y;
        hr[2] = (_Float16)vr.z; hr[3] = (_Float16)vr.w;
        *reinterpret_cast<half4v*>(&kv[chS * 128 + 4 * npS]) = hs;
        *reinterpret_cast<half4v*>(&kv[chR * 128 + 4 * npR]) = hr;
    }
    __syncthreads();

    // ---- drain: full 512B records, 64KiB contiguous per block ----
    _Float16* dbase = KV + (size_t)z * HW * 256;
    const int u  = tid & 31;             // ch-group: ch = 8u..8u+7
    const int rl = tid >> 5;             // record within pass (0..7)
    #pragma unroll
    for (int p = 0; p < 16; ++p) {
        const int nn = rl + 8 * p;       // 0..127
        const int q  = nn >> 2;
        const int rm = nn & 3;
        half8 hv;
        #pragma unroll
        for (int i = 0; i < 8; ++i) {
            const int ch = 8 * u + i;    // ch>>3 == u for i<8
            hv[i] = kv[ch * 128 + ((q ^ u) << 2) + rm];
        }
        *reinterpret_cast<half8*>(&dbase[(size_t)(n0 + nn) * 256 + 8 * u]) = hv;
    }
}

// Fused single-pass gather attention from interleaved fp16 KV rows.
// Per 16-lane group (one position p): for each of 16 gather rows, the group
// loads the full 512B K|V record cooperatively (2x16B per lane), computes the
// score via butterfly reduce, and online-softmax-accumulates V (flash-style
// running m, l). 8 rows (16 loads/lane) in flight to hide gather latency.
__global__ __launch_bounds__(256) void attn_gather_kv(
    const float* __restrict__ Q, const int* __restrict__ Pos,
    const _Float16* __restrict__ KV,
    float* __restrict__ outBuf, float* __restrict__ outM, int b0)
{
    __shared__ float q_s[P_TILE][132];   // Q tile, fp32, padded
    __shared__ float out_s[P_TILE][132];

    const int tid = threadIdx.x;
    const int bb  = blockIdx.x / BLOCKS_PER_BATCH;   // batch within this launch
    const int b   = b0 + bb;                         // absolute batch
    const int p0  = (blockIdx.x % BLOCKS_PER_BATCH) * P_TILE;

    // ---- stage Q tile (coalesced) ----
    for (int i = tid; i < P_TILE * C; i += 256) {
        int c = i >> 4, pl0 = i & 15;
        q_s[pl0][c] = Q[((size_t)(b * C + c)) * hw + p0 + pl0];
    }
    const int pl = tid >> 4;   // position in tile (= 16-lane group id)
    const int cg = tid & 15;   // lane within group
    const int p  = p0 + pl;
    int myidx;
    {
        const int rr = Pos[(((size_t)(b * 2 + 0) * hw) + p) * K + cg];   // coalesced
        const int cc = Pos[(((size_t)(b * 2 + 1) * hw) + p) * K + cg];
        myidx = rr * W_ + cc;
    }
    __syncthreads();

    float qf[8];
    #pragma unroll
    for (int i = 0; i < 8; ++i) qf[i] = q_s[pl][cg * 8 + i];

    float m = -1e30f, l = 0.f, myscore = 0.f;
    float acc[8];
    #pragma unroll
    for (int i = 0; i < 8; ++i) acc[i] = 0.f;

    const half8* base = reinterpret_cast<const half8*>(KV) + (size_t)bb * HW * 32;

    #pragma unroll
    for (int kc = 0; kc < K; kc += 8) {          // 8-row chunks: 16 loads in flight
        half8 kreg[8], vreg[8];
        #pragma unroll
        for (int r = 0; r < 8; ++r) {
            const int ridx = __shfl(myidx, kc + r, 16);    // group-uniform row idx
            const half8* row = base + (size_t)ridx * 32;   // 512B record, 512B aligned
            kreg[r] = row[cg];        // K halfs [cg*8, cg*8+8)
            vreg[r] = row[16 + cg];   // V halfs [cg*8, cg*8+8)
        }
        #pragma unroll
        for (int r = 0; r < 8; ++r) {
            float part = 0.f;
            #pragma unroll
            for (int i = 0; i < 8; ++i) part += qf[i] * (float)kreg[r][i];
            #pragma unroll
            for (int off = 1; off < 16; off <<= 1) part += __shfl_xor(part, off);
            // 'part' = score of row kc+r, identical across the 16-lane group
            const float mn    = fmaxf(m, part);
            const float scale = __expf(m - mn);      // ==1 when max unchanged; 0 on first row
            const float e     = __expf(part - mn);
            l = l * scale + e;
            #pragma unroll
            for (int i = 0; i < 8; ++i) acc[i] = acc[i] * scale + e * (float)vreg[r][i];
            m = mn;
            if (cg == kc + r) myscore = part;
        }
    }

    const float inv_l = 1.0f / l;
    const float attn  = __expf(myscore - m) * inv_l;   // == e_k / sum_k e_k
    outM[((size_t)b * hw + p) * K + cg] = attn;        // coalesced
    #pragma unroll
    for (int i = 0; i < 8; ++i) out_s[pl][cg * 8 + i] = acc[i] * inv_l;
    __syncthreads();
    for (int i = tid; i < P_TILE * C; i += 256) {
        int c = i >> 4, pl3 = i & 15;
        outBuf[((size_t)(b * C + c)) * hw + p0 + pl3] = out_s[pl3][c];   // coalesced
    }
}

// Fallback: direct gather from original (B,C,H,W) layout. Slow but needs no workspace.
__global__ __launch_bounds__(256) void attn_direct(
    const float* __restrict__ Q, const float* __restrict__ S, const float* __restrict__ R,
    const int* __restrict__ Pos, float* __restrict__ outBuf, float* __restrict__ outM)
{
    __shared__ float q_s[P_TILE][132];
    __shared__ float attn_s[P_TILE][17];
    __shared__ int   idx_s[P_TILE][K];
    __shared__ float out_s[P_TILE][132];

    const int tid = threadIdx.x;
    const int b   = blockIdx.x / BLOCKS_PER_BATCH;
    const int p0  = (blockIdx.x % BLOCKS_PER_BATCH) * P_TILE;

    for (int i = tid; i < P_TILE * C; i += 256) {
        int c = i >> 4, pl0 = i & 15;
        q_s[pl0][c] = Q[((size_t)(b * C + c)) * hw + p0 + pl0];
    }
    const int pl = tid >> 4;
    const int kk = tid & 15;
    const int p  = p0 + pl;
    const int rr = Pos[(((size_t)(b * 2 + 0) * hw) + p) * K + kk];
    const int cc = Pos[(((size_t)(b * 2 + 1) * hw) + p) * K + kk];
    const int idx = rr * W_ + cc;
    idx_s[pl][kk] = idx;
    __syncthreads();

    float score = 0.f;
    {
        const float* srow = S + (size_t)b * C * HW + idx;
        for (int c = 0; c < C; ++c) score += q_s[pl][c] * srow[(size_t)c * HW];
    }
    float mx = score;
    #pragma unroll
    for (int off = 1; off < 16; off <<= 1) mx = fmaxf(mx, __shfl_xor(mx, off));
    float e = __expf(score - mx);
    float ssum = e;
    #pragma unroll
    for (int off = 1; off < 16; off <<= 1) ssum += __shfl_xor(ssum, off);
    const float attn = e / ssum;
    outM[((size_t)b * hw + p) * K + kk] = attn;
    attn_s[pl][kk] = attn;
    __syncthreads();

    {
        const int pl2 = tid >> 4;
        const int cg  = tid & 15;
        float acc[8];
        #pragma unroll
        for (int i = 0; i < 8; ++i) acc[i] = 0.f;
        for (int k2 = 0; k2 < K; ++k2) {
            const float a = attn_s[pl2][k2];
            const float* rw = R + (size_t)b * C * HW + idx_s[pl2][k2];
            #pragma unroll
            for (int i = 0; i < 8; ++i) acc[i] += a * rw[(size_t)(cg * 8 + i) * HW];
        }
        #pragma unroll
        for (int i = 0; i < 8; ++i) out_s[pl2][cg * 8 + i] = acc[i];
    }
    __syncthreads();
    for (int i = tid; i < P_TILE * C; i += 256) {
        int c = i >> 4, pl3 = i & 15;
        outBuf[((size_t)(b * C + c)) * hw + p0 + pl3] = out_s[pl3][c];
    }
}

extern "C" void kernel_launch(void* const* d_in, const int* in_sizes, int n_in,
                              void* d_out, int out_size, void* d_ws, size_t ws_size,
                              hipStream_t stream)
{
    (void)in_sizes; (void)n_in; (void)out_size;
    const float* Q  = (const float*)d_in[0];
    const float* S  = (const float*)d_in[1];
    const float* R  = (const float*)d_in[2];
    const int*  Pos = (const int*)d_in[3];
    float* outBuf = (float*)d_out;
    float* outM   = outBuf + (size_t)B * C * hw;   // buffer is B*Cv*h*w elements

    const size_t fullBytes     = (size_t)B * HW * 256 * sizeof(_Float16);  // 128 MiB
    const size_t perBatchBytes = (size_t)HW * 256 * sizeof(_Float16);      // 32 MiB

    dim3 tb(256);
    if (ws_size >= fullBytes) {
        // convert+interleave all batches in one launch, then one fused compute launch
        _Float16* KVt = (_Float16*)d_ws;
        dim3 tg(HW / 128, 1, B);
        transpose_kv_f16<<<tg, tb, 0, stream>>>(S, R, KVt);
        attn_gather_kv<<<dim3(B * BLOCKS_PER_BATCH), 256, 0, stream>>>(
            Q, Pos, KVt, outBuf, outM, 0);
    } else if (ws_size >= perBatchBytes) {
        // per-batch convert + compute, workspace reused
        _Float16* KVt = (_Float16*)d_ws;
        dim3 tg(HW / 128, 1, 1);
        for (int b = 0; b < B; ++b) {
            transpose_kv_f16<<<tg, tb, 0, stream>>>(
                S + (size_t)b * C * HW, R + (size_t)b * C * HW, KVt);
            attn_gather_kv<<<dim3(BLOCKS_PER_BATCH), 256, 0, stream>>>(
                Q, Pos, KVt, outBuf, outM, b);
        }
    } else {
        // no usable workspace: direct (uncoalesced) fp32 gather
        attn_direct<<<dim3(B * BLOCKS_PER_BATCH), 256, 0, stream>>>(
            Q, S, R, Pos, outBuf, outM);
    }
}